// Round 6
// baseline (783.222 us; speedup 1.0000x reference)
//
#include <hip/hip_runtime.h>
#include <math.h>

// GaussianSampleST split into 2 kernels (fp32):
//  A) glimpse_kernel: per-source glimpse g[n][t][c][32][22] (gamma folded),
//     computed ONCE per source instead of ~2x (each tq re-derived its t0/t1
//     sources in the fused version -> ~2x redundant GEMM work).
//     Inner structure = round-4 verified code (2 h-rows/thread GEMM1, t2s
//     stride 26, h-halved staging).
//  B) gather_kernel: out[n][c][tq] = W0*g[t0] + W1*g[t1] with zero-padding,
//     pure float4 streaming (memory-bound).
// Fallback: if ws_size < 86.5MB, launch the fused round-4 kernel.

#define EPS_ 1e-8f
#define GLIMPSE_BYTES (16ull * 30ull * 64ull * 704ull * 4ull)  // 86,507,520

// ---------------------------------------------------------------- kernel A
__global__ __launch_bounds__(256) void glimpse_kernel(
    const float* __restrict__ x,
    const float* __restrict__ dx,  const float* __restrict__ dy,
    const float* __restrict__ ls2, const float* __restrict__ ld,
    const float* __restrict__ lg,
    float* __restrict__ g)
{
    __shared__ float FyT[64][32];     // [h][i]  (Fy, pre-scaled by gamma)
    __shared__ float FxT[44][24];     // [w][j]  (cols 22/23 zeroed)
    __shared__ float t2s[8][32][26];  // [c][h-in-half][j], stride 26

    const int tid = threadIdx.x;
    int b = blockIdx.x;
    const int cg = b & 7; b >>= 3;
    const int t  = b % 30;
    const int n  = b / 30;
    const int nt = n * 30 + t;

    const int c_loc = tid >> 5;        // 0..7
    const int hl    = tid & 31;        // GEMM1: rows h=hl and h=32+hl
    const int jt    = tid & 3;         // GEMM2: j-tile base 6*jt
    const int it    = (tid >> 2) & 7;  // GEMM2: i-tile base 4*it
    const int j0    = 6 * jt;
    const int i0r   = 4 * it;

    // ---- per-source attention params into LDS (all 256 lanes) ----
    const float sigma2 = expf(ls2[nt]);
    const float inv2s2 = 0.5f / sigma2;
    const float delta  = expf(ld[nt]);
    const float gamma  = 1.f / (1.f + expf(-lg[nt]));

    if (tid < 128) {
        // Fy: col i = tid>>2 (0..31), quarter q = tid&3 covers h = 16q..16q+15
        const int i = tid >> 2, q = tid & 3;
        float pod = dy[nt] + 0.5f * (t >= 1 ? dy[nt - 1] : 0.f)
                           + 0.5f * (t >= 2 ? dy[nt - 2] : 0.f);
        const float mu = tanhf(pod) * 32.f + 32.f + ((float)i - 16.f) * delta;
        float e[16];
        float sum = 0.f;
#pragma unroll
        for (int k = 0; k < 16; ++k) {
            const float d = (float)(16 * q + k) - mu;
            e[k] = expf(-d * d * inv2s2);
            sum += e[k];
        }
        sum += __shfl_xor(sum, 1);
        sum += __shfl_xor(sum, 2);
        const float sc = gamma / fmaxf(sum, EPS_);
#pragma unroll
        for (int k = 0; k < 16; ++k)
            FyT[16 * q + k][i] = e[k] * sc;
    } else {
        // Fx: col j = (tid-128)>>2, quarter q covers w = 11q..11q+10
        const int tx = tid - 128;
        const int j = tx >> 2, q = tx & 3;
        float pod = dx[nt] + 0.5f * (t >= 1 ? dx[nt - 1] : 0.f)
                           + 0.5f * (t >= 2 ? dx[nt - 2] : 0.f);
        const float mu = tanhf(pod) * 22.f + 22.f + ((float)j - 11.f) * delta;
        float e[11];
        float sum = 0.f;
#pragma unroll
        for (int m = 0; m < 11; ++m) {
            const float d = (float)(11 * q + m) - mu;
            e[m] = expf(-d * d * inv2s2);
            sum += e[m];
        }
        sum += __shfl_xor(sum, 1);
        sum += __shfl_xor(sum, 2);
        const float sc = 1.f / fmaxf(sum, EPS_);
        if (j < 22) {
#pragma unroll
            for (int m = 0; m < 11; ++m)
                FxT[11 * q + m][j] = e[m] * sc;
        }
    }
    if (tid < 88) {
        FxT[tid >> 1][22 + (tid & 1)] = 0.f;   // pad cols read-safe
    }
    __syncthreads();

    float acc2[4][6];
#pragma unroll
    for (int r = 0; r < 4; ++r)
#pragma unroll
        for (int s2 = 0; s2 < 6; ++s2) acc2[r][s2] = 0.f;

    // ---- GEMM1 (all 256 threads): rows h=hl (->a0), h=32+hl (->a1),
    //      one FxT streaming pass serves both rows.
    float a0[22], a1[22];
#pragma unroll
    for (int j = 0; j < 22; ++j) { a0[j] = 0.f; a1[j] = 0.f; }
    {
        const size_t xoff =
            ((((size_t)n * 64 + (size_t)(cg * 8 + c_loc)) * 30
              + (size_t)t) * 64 + (size_t)hl) * 44;
        const float4* xr0 = reinterpret_cast<const float4*>(x + xoff);
        const float4* xr1 = reinterpret_cast<const float4*>(x + xoff + 32 * 44);

#pragma unroll 2
        for (int wi = 0; wi < 11; ++wi) {
            const float4 xa = xr0[wi];
            const float4 xb = xr1[wi];
            const float xav[4] = { xa.x, xa.y, xa.z, xa.w };
            const float xbv[4] = { xb.x, xb.y, xb.z, xb.w };
#pragma unroll
            for (int k = 0; k < 4; ++k) {
                const float4* fxr =
                    reinterpret_cast<const float4*>(&FxT[4 * wi + k][0]);
                const float4 f0 = fxr[0], f1 = fxr[1], f2 = fxr[2],
                             f3 = fxr[3], f4 = fxr[4];
                const float2 f5 =
                    *reinterpret_cast<const float2*>(&FxT[4 * wi + k][20]);
                const float fv[22] = { f0.x, f0.y, f0.z, f0.w,
                                       f1.x, f1.y, f1.z, f1.w,
                                       f2.x, f2.y, f2.z, f2.w,
                                       f3.x, f3.y, f3.z, f3.w,
                                       f4.x, f4.y, f4.z, f4.w,
                                       f5.x, f5.y };
                const float va = xav[k], vb = xbv[k];
#pragma unroll
                for (int j = 0; j < 22; ++j) {
                    a0[j] += va * fv[j];
                    a1[j] += vb * fv[j];
                }
            }
        }
    }

    // ---- half 0: store a0, consume via GEMM2 (Fy rows 0..31) ----
    {
        float2* d0 = reinterpret_cast<float2*>(&t2s[c_loc][hl][0]);
#pragma unroll
        for (int p = 0; p < 11; ++p)
            d0[p] = make_float2(a0[2 * p], a0[2 * p + 1]);
        d0[11] = make_float2(0.f, 0.f);
    }
    __syncthreads();
    {
#pragma unroll 4
        for (int hp2 = 0; hp2 < 32; ++hp2) {
            const float4 fy = *reinterpret_cast<const float4*>(&FyT[hp2][i0r]);
            const float2* tp =
                reinterpret_cast<const float2*>(&t2s[c_loc][hp2][j0]);
            const float2 q0 = tp[0], q1 = tp[1], q2 = tp[2];
            const float fyv[4] = { fy.x, fy.y, fy.z, fy.w };
            const float tv[6]  = { q0.x, q0.y, q1.x, q1.y, q2.x, q2.y };
#pragma unroll
            for (int r = 0; r < 4; ++r)
#pragma unroll
                for (int s2 = 0; s2 < 6; ++s2)
                    acc2[r][s2] += fyv[r] * tv[s2];
        }
    }
    __syncthreads();

    // ---- half 1: store a1, consume via GEMM2 (Fy rows 32..63) ----
    {
        float2* d1 = reinterpret_cast<float2*>(&t2s[c_loc][hl][0]);
#pragma unroll
        for (int p = 0; p < 11; ++p)
            d1[p] = make_float2(a1[2 * p], a1[2 * p + 1]);
        d1[11] = make_float2(0.f, 0.f);
    }
    __syncthreads();
    {
#pragma unroll 4
        for (int hp2 = 0; hp2 < 32; ++hp2) {
            const float4 fy =
                *reinterpret_cast<const float4*>(&FyT[32 + hp2][i0r]);
            const float2* tp =
                reinterpret_cast<const float2*>(&t2s[c_loc][hp2][j0]);
            const float2 q0 = tp[0], q1 = tp[1], q2 = tp[2];
            const float fyv[4] = { fy.x, fy.y, fy.z, fy.w };
            const float tv[6]  = { q0.x, q0.y, q1.x, q1.y, q2.x, q2.y };
#pragma unroll
            for (int r = 0; r < 4; ++r)
#pragma unroll
                for (int s2 = 0; s2 < 6; ++s2)
                    acc2[r][s2] += fyv[r] * tv[s2];
        }
    }

    // ---- store glimpse tile: g[nt][c][i][j], 32x22 per channel ----
    const size_t gb = ((size_t)nt * 64 + (size_t)(cg * 8 + c_loc)) * 704;
#pragma unroll
    for (int r = 0; r < 4; ++r) {
#pragma unroll
        for (int s2 = 0; s2 < 6; ++s2) {
            const int j = j0 + s2;
            if (j < 22) {
                g[gb + (size_t)((i0r + r) * 22 + j)] = acc2[r][s2];
            }
        }
    }
}

// ---------------------------------------------------------------- kernel B
__global__ __launch_bounds__(256) void gather_kernel(
    const float* __restrict__ g,
    const float* __restrict__ dtp, const float* __restrict__ ldt,
    const float* __restrict__ lgt,
    float* __restrict__ out)
{
    const int tid = threadIdx.x;
    int b = blockIdx.x;
    const int cg = b & 7; b >>= 3;
    const int tq = b % 30;
    const int n  = b / 30;

    const float dtv     = tanhf(dtp[n]) * 15.f + 15.f;
    const float delta_t = expf(ldt[n]);
    const float gamma_t = 1.f / (1.f + expf(-lgt[n]));
    float mu_t = dtv + ((float)tq - 15.f) * delta_t;
    mu_t = mu_t / 29.f * 2.f - 1.f;
    const float iy  = ((mu_t + 1.f) * 30.f - 1.f) * 0.5f;
    const float iy0 = floorf(iy);
    const float w1  = iy - iy0;
    const int   i0  = (int)iy0;
    const int   i1  = i0 + 1;
    const float W0 = (i0 >= 0 && i0 < 30) ? 0.5f * gamma_t * (1.f - w1) : 0.f;
    const float W1 = (i1 >= 0 && i1 < 30) ? 0.5f * gamma_t * w1 : 0.f;
    const int t0 = min(max(i0, 0), 29);
    const int t1 = min(max(i1, 0), 29);
    const int nt0 = n * 30 + t0;
    const int nt1 = n * 30 + t1;

    const float4* g4 = reinterpret_cast<const float4*>(g);
    float4*       o4 = reinterpret_cast<float4*>(out);

    // main rows: out floats 176..879 per (n,c,tq)  <-  g floats 0..703
    for (int idx = tid; idx < 8 * 176; idx += 256) {
        const int cl = idx / 176, k = idx % 176;
        const int c  = cg * 8 + cl;
        const float4 ga = g4[((size_t)nt0 * 64 + c) * 176 + k];
        const float4 gb = g4[((size_t)nt1 * 64 + c) * 176 + k];
        float4 r;
        r.x = W0 * ga.x + W1 * gb.x;
        r.y = W0 * ga.y + W1 * gb.y;
        r.z = W0 * ga.z + W1 * gb.z;
        r.w = W0 * ga.w + W1 * gb.w;
        o4[(((size_t)n * 64 + c) * 30 + tq) * 264 + 44 + k] = r;
    }
    // pad rows: float4 0..43 (rows 0..7) and 220..263 (rows 40..47)
    for (int idx = tid; idx < 8 * 88; idx += 256) {
        const int cl = idx / 88, k = idx % 88;
        const int c  = cg * 8 + cl;
        const int off = (k < 44) ? k : (k + 176);
        o4[(((size_t)n * 64 + c) * 30 + tq) * 264 + off] =
            make_float4(0.f, 0.f, 0.f, 0.f);
    }
}

// ------------------------------------------------- fallback (round-4 fused)
__global__ __launch_bounds__(256) void gst_fallback(
    const float* __restrict__ x,
    const float* __restrict__ dx,  const float* __restrict__ dy,
    const float* __restrict__ ls2, const float* __restrict__ ld,
    const float* __restrict__ lg,
    const float* __restrict__ dtp, const float* __restrict__ ldt,
    const float* __restrict__ lgt,
    float* __restrict__ out)
{
    __shared__ float FyT[64][32];
    __shared__ float FxT[44][24];
    __shared__ float t2s[8][32][26];

    const int tid = threadIdx.x;
    int b = blockIdx.x;
    const int cg = b & 7; b >>= 3;
    const int tq = b % 30;
    const int n  = b / 30;

    const float dtv     = tanhf(dtp[n]) * 15.f + 15.f;
    const float delta_t = expf(ldt[n]);
    const float gamma_t = 1.f / (1.f + expf(-lgt[n]));
    float mu_t = dtv + ((float)tq - 15.f) * delta_t;
    mu_t = mu_t / 29.f * 2.f - 1.f;
    const float iy  = ((mu_t + 1.f) * 30.f - 1.f) * 0.5f;
    const float iy0 = floorf(iy);
    const float w1  = iy - iy0;
    const int   i0  = (int)iy0;
    const int   i1  = i0 + 1;
    const float W0 = (i0 >= 0 && i0 < 30) ? 0.5f * gamma_t * (1.f - w1) : 0.f;
    const float W1 = (i1 >= 0 && i1 < 30) ? 0.5f * gamma_t * w1 : 0.f;
    const int t0 = min(max(i0, 0), 29);
    const int t1 = min(max(i1, 0), 29);

    const int c_loc = tid >> 5;
    const int hl    = tid & 31;
    const int jt    = tid & 3;
    const int it    = (tid >> 2) & 7;
    const int j0    = 6 * jt;
    const int i0r   = 4 * it;

    const size_t ob =
        (((size_t)n * 64 + (size_t)(cg * 8)) * 30 + (size_t)tq) * 1056;
    for (int idx = tid; idx < 8 * 16 * 22; idx += 256) {
        const int c   = idx / 352;
        const int rem = idx % 352;
        const int r   = rem / 22;
        const int j   = rem % 22;
        const int ip  = (r < 8) ? r : (r + 32);
        out[ob + (size_t)c * 31680 + (size_t)(ip * 22 + j)] = 0.f;
    }

    float acc2[4][6];
#pragma unroll
    for (int r = 0; r < 4; ++r)
#pragma unroll
        for (int s2 = 0; s2 < 6; ++s2) acc2[r][s2] = 0.f;

    bool first = true;
#pragma unroll 1
    for (int s = 0; s < 2; ++s) {
        const float Ws = s ? W1 : W0;
        const int   ts = s ? t1 : t0;
        if (Ws == 0.f) continue;
        if (!first) __syncthreads();
        first = false;

        const int nt = n * 30 + ts;
        const float sigma2 = expf(ls2[nt]);
        const float inv2s2 = 0.5f / sigma2;
        const float delta  = expf(ld[nt]);
        const float gamma  = 1.f / (1.f + expf(-lg[nt]));
        const float A      = Ws * gamma;

        if (tid < 128) {
            const int i = tid >> 2, q = tid & 3;
            float pod = dy[nt] + 0.5f * (ts >= 1 ? dy[nt - 1] : 0.f)
                               + 0.5f * (ts >= 2 ? dy[nt - 2] : 0.f);
            const float mu = tanhf(pod) * 32.f + 32.f + ((float)i - 16.f) * delta;
            float e[16];
            float sum = 0.f;
#pragma unroll
            for (int k = 0; k < 16; ++k) {
                const float d = (float)(16 * q + k) - mu;
                e[k] = expf(-d * d * inv2s2);
                sum += e[k];
            }
            sum += __shfl_xor(sum, 1);
            sum += __shfl_xor(sum, 2);
            const float sc = A / fmaxf(sum, EPS_);
#pragma unroll
            for (int k = 0; k < 16; ++k)
                FyT[16 * q + k][i] = e[k] * sc;
        } else {
            const int tx = tid - 128;
            const int j = tx >> 2, q = tx & 3;
            float pod = dx[nt] + 0.5f * (ts >= 1 ? dx[nt - 1] : 0.f)
                               + 0.5f * (ts >= 2 ? dx[nt - 2] : 0.f);
            const float mu = tanhf(pod) * 22.f + 22.f + ((float)j - 11.f) * delta;
            float e[11];
            float sum = 0.f;
#pragma unroll
            for (int m = 0; m < 11; ++m) {
                const float d = (float)(11 * q + m) - mu;
                e[m] = expf(-d * d * inv2s2);
                sum += e[m];
            }
            sum += __shfl_xor(sum, 1);
            sum += __shfl_xor(sum, 2);
            const float sc = 1.f / fmaxf(sum, EPS_);
            if (j < 22) {
#pragma unroll
                for (int m = 0; m < 11; ++m)
                    FxT[11 * q + m][j] = e[m] * sc;
            }
        }
        if (tid < 88) {
            FxT[tid >> 1][22 + (tid & 1)] = 0.f;
        }
        __syncthreads();

        float a0[22], a1[22];
#pragma unroll
        for (int j = 0; j < 22; ++j) { a0[j] = 0.f; a1[j] = 0.f; }
        {
            const size_t xoff =
                ((((size_t)n * 64 + (size_t)(cg * 8 + c_loc)) * 30
                  + (size_t)ts) * 64 + (size_t)hl) * 44;
            const float4* xr0 = reinterpret_cast<const float4*>(x + xoff);
            const float4* xr1 = reinterpret_cast<const float4*>(x + xoff + 32 * 44);

#pragma unroll 2
            for (int wi = 0; wi < 11; ++wi) {
                const float4 xa = xr0[wi];
                const float4 xb = xr1[wi];
                const float xav[4] = { xa.x, xa.y, xa.z, xa.w };
                const float xbv[4] = { xb.x, xb.y, xb.z, xb.w };
#pragma unroll
                for (int k = 0; k < 4; ++k) {
                    const float4* fxr =
                        reinterpret_cast<const float4*>(&FxT[4 * wi + k][0]);
                    const float4 f0 = fxr[0], f1 = fxr[1], f2 = fxr[2],
                                 f3 = fxr[3], f4 = fxr[4];
                    const float2 f5 =
                        *reinterpret_cast<const float2*>(&FxT[4 * wi + k][20]);
                    const float fv[22] = { f0.x, f0.y, f0.z, f0.w,
                                           f1.x, f1.y, f1.z, f1.w,
                                           f2.x, f2.y, f2.z, f2.w,
                                           f3.x, f3.y, f3.z, f3.w,
                                           f4.x, f4.y, f4.z, f4.w,
                                           f5.x, f5.y };
                    const float va = xav[k], vb = xbv[k];
#pragma unroll
                    for (int j = 0; j < 22; ++j) {
                        a0[j] += va * fv[j];
                        a1[j] += vb * fv[j];
                    }
                }
            }
        }

        {
            float2* d0 = reinterpret_cast<float2*>(&t2s[c_loc][hl][0]);
#pragma unroll
            for (int p = 0; p < 11; ++p)
                d0[p] = make_float2(a0[2 * p], a0[2 * p + 1]);
            d0[11] = make_float2(0.f, 0.f);
        }
        __syncthreads();
        {
#pragma unroll 4
            for (int hp2 = 0; hp2 < 32; ++hp2) {
                const float4 fy =
                    *reinterpret_cast<const float4*>(&FyT[hp2][i0r]);
                const float2* tp =
                    reinterpret_cast<const float2*>(&t2s[c_loc][hp2][j0]);
                const float2 q0 = tp[0], q1 = tp[1], q2 = tp[2];
                const float fyv[4] = { fy.x, fy.y, fy.z, fy.w };
                const float tv[6]  = { q0.x, q0.y, q1.x, q1.y, q2.x, q2.y };
#pragma unroll
                for (int r = 0; r < 4; ++r)
#pragma unroll
                    for (int s2 = 0; s2 < 6; ++s2)
                        acc2[r][s2] += fyv[r] * tv[s2];
            }
        }
        __syncthreads();

        {
            float2* d1 = reinterpret_cast<float2*>(&t2s[c_loc][hl][0]);
#pragma unroll
            for (int p = 0; p < 11; ++p)
                d1[p] = make_float2(a1[2 * p], a1[2 * p + 1]);
            d1[11] = make_float2(0.f, 0.f);
        }
        __syncthreads();
        {
#pragma unroll 4
            for (int hp2 = 0; hp2 < 32; ++hp2) {
                const float4 fy =
                    *reinterpret_cast<const float4*>(&FyT[32 + hp2][i0r]);
                const float2* tp =
                    reinterpret_cast<const float2*>(&t2s[c_loc][hp2][j0]);
                const float2 q0 = tp[0], q1 = tp[1], q2 = tp[2];
                const float fyv[4] = { fy.x, fy.y, fy.z, fy.w };
                const float tv[6]  = { q0.x, q0.y, q1.x, q1.y, q2.x, q2.y };
#pragma unroll
                for (int r = 0; r < 4; ++r)
#pragma unroll
                    for (int s2 = 0; s2 < 6; ++s2)
                        acc2[r][s2] += fyv[r] * tv[s2];
            }
        }
    }

#pragma unroll
    for (int r = 0; r < 4; ++r) {
#pragma unroll
        for (int s2 = 0; s2 < 6; ++s2) {
            const int j = j0 + s2;
            if (j < 22) {
                out[ob + (size_t)c_loc * 31680
                       + (size_t)((8 + i0r + r) * 22 + j)] = acc2[r][s2];
            }
        }
    }
}

extern "C" void kernel_launch(void* const* d_in, const int* in_sizes, int n_in,
                              void* d_out, int out_size, void* d_ws, size_t ws_size,
                              hipStream_t stream) {
    const float* x   = (const float*)d_in[0];
    const float* dx  = (const float*)d_in[1];
    const float* dy  = (const float*)d_in[2];
    const float* ls2 = (const float*)d_in[3];
    const float* ld  = (const float*)d_in[4];
    const float* lg  = (const float*)d_in[5];
    const float* dtp = (const float*)d_in[6];
    const float* ldt = (const float*)d_in[7];
    const float* lgt = (const float*)d_in[8];
    float* out = (float*)d_out;

    dim3 grid(16 * 30 * 8), block(256);

    if (d_ws != nullptr && ws_size >= GLIMPSE_BYTES) {
        float* g = (float*)d_ws;
        hipLaunchKernelGGL(glimpse_kernel, grid, block, 0, stream,
                           x, dx, dy, ls2, ld, lg, g);
        hipLaunchKernelGGL(gather_kernel, grid, block, 0, stream,
                           g, dtp, ldt, lgt, out);
    } else {
        hipLaunchKernelGGL(gst_fallback, grid, block, 0, stream,
                           x, dx, dy, ls2, ld, lg, dtp, ldt, lgt, out);
    }
}

// Round 7
// 782.157 us; speedup vs baseline: 1.0014x; 1.0014x over previous
//
#include <hip/hip_runtime.h>
#include <math.h>

// GaussianSampleST split into 2 kernels (fp32):
//  A) glimpse_kernel: per-source glimpse g[n][t][c][32][22] (gamma folded),
//     computed ONCE per source instead of ~2x.  Round-4 verified inner
//     structure.  amdgpu_waves_per_eu(2,4) pins the register allocator:
//     round-6 compiled this body to 60 VGPR + scratch spill (FETCH 1.2GB,
//     387us); the s-loop version of the same body compiles to 124 VGPR
//     spill-free.  max=4 waves/EU stops the 8-wave squeeze; min=2 keeps
//     the cap at 256 so nothing is forced to spill.
//  B) gather_kernel: out[n][c][tq] = W0*g[t0] + W1*g[t1] + zero-pad,
//     pure float4 streaming (memory-bound).
// Fallback: if ws_size < 86.5MB, launch the fused round-4 kernel.

#define EPS_ 1e-8f
#define GLIMPSE_BYTES (16ull * 30ull * 64ull * 704ull * 4ull)  // 86,507,520

// ---------------------------------------------------------------- kernel A
__global__ __launch_bounds__(256)
__attribute__((amdgpu_waves_per_eu(2, 4)))
void glimpse_kernel(
    const float* __restrict__ x,
    const float* __restrict__ dx,  const float* __restrict__ dy,
    const float* __restrict__ ls2, const float* __restrict__ ld,
    const float* __restrict__ lg,
    float* __restrict__ g)
{
    __shared__ float FyT[64][32];     // [h][i]  (Fy, pre-scaled by gamma)
    __shared__ float FxT[44][24];     // [w][j]  (cols 22/23 zeroed)
    __shared__ float t2s[8][32][26];  // [c][h-in-half][j], stride 26

    const int tid = threadIdx.x;
    int b = blockIdx.x;
    const int cg = b & 7; b >>= 3;
    const int t  = b % 30;
    const int n  = b / 30;
    const int nt = n * 30 + t;

    const int c_loc = tid >> 5;        // 0..7
    const int hl    = tid & 31;        // GEMM1: rows h=hl and h=32+hl
    const int jt    = tid & 3;         // GEMM2: j-tile base 6*jt
    const int it    = (tid >> 2) & 7;  // GEMM2: i-tile base 4*it
    const int j0    = 6 * jt;
    const int i0r   = 4 * it;

    // ---- per-source attention params into LDS (all 256 lanes) ----
    const float sigma2 = expf(ls2[nt]);
    const float inv2s2 = 0.5f / sigma2;
    const float delta  = expf(ld[nt]);
    const float gamma  = 1.f / (1.f + expf(-lg[nt]));

    if (tid < 128) {
        // Fy: col i = tid>>2 (0..31), quarter q = tid&3 covers h = 16q..16q+15
        const int i = tid >> 2, q = tid & 3;
        float pod = dy[nt] + 0.5f * (t >= 1 ? dy[nt - 1] : 0.f)
                           + 0.5f * (t >= 2 ? dy[nt - 2] : 0.f);
        const float mu = tanhf(pod) * 32.f + 32.f + ((float)i - 16.f) * delta;
        float e[16];
        float sum = 0.f;
#pragma unroll
        for (int k = 0; k < 16; ++k) {
            const float d = (float)(16 * q + k) - mu;
            e[k] = expf(-d * d * inv2s2);
            sum += e[k];
        }
        sum += __shfl_xor(sum, 1);
        sum += __shfl_xor(sum, 2);
        const float sc = gamma / fmaxf(sum, EPS_);
#pragma unroll
        for (int k = 0; k < 16; ++k)
            FyT[16 * q + k][i] = e[k] * sc;
    } else {
        // Fx: col j = (tid-128)>>2, quarter q covers w = 11q..11q+10
        const int tx = tid - 128;
        const int j = tx >> 2, q = tx & 3;
        float pod = dx[nt] + 0.5f * (t >= 1 ? dx[nt - 1] : 0.f)
                           + 0.5f * (t >= 2 ? dx[nt - 2] : 0.f);
        const float mu = tanhf(pod) * 22.f + 22.f + ((float)j - 11.f) * delta;
        float e[11];
        float sum = 0.f;
#pragma unroll
        for (int m = 0; m < 11; ++m) {
            const float d = (float)(11 * q + m) - mu;
            e[m] = expf(-d * d * inv2s2);
            sum += e[m];
        }
        sum += __shfl_xor(sum, 1);
        sum += __shfl_xor(sum, 2);
        const float sc = 1.f / fmaxf(sum, EPS_);
        if (j < 22) {
#pragma unroll
            for (int m = 0; m < 11; ++m)
                FxT[11 * q + m][j] = e[m] * sc;
        }
    }
    if (tid < 88) {
        FxT[tid >> 1][22 + (tid & 1)] = 0.f;   // pad cols read-safe
    }
    __syncthreads();

    float acc2[4][6];
#pragma unroll
    for (int r = 0; r < 4; ++r)
#pragma unroll
        for (int s2 = 0; s2 < 6; ++s2) acc2[r][s2] = 0.f;

    // ---- GEMM1 (all 256 threads): rows h=hl (->a0), h=32+hl (->a1),
    //      one FxT streaming pass serves both rows.
    float a0[22], a1[22];
#pragma unroll
    for (int j = 0; j < 22; ++j) { a0[j] = 0.f; a1[j] = 0.f; }
    {
        const size_t xoff =
            ((((size_t)n * 64 + (size_t)(cg * 8 + c_loc)) * 30
              + (size_t)t) * 64 + (size_t)hl) * 44;
        const float4* xr0 = reinterpret_cast<const float4*>(x + xoff);
        const float4* xr1 = reinterpret_cast<const float4*>(x + xoff + 32 * 44);

#pragma unroll 2
        for (int wi = 0; wi < 11; ++wi) {
            const float4 xa = xr0[wi];
            const float4 xb = xr1[wi];
            const float xav[4] = { xa.x, xa.y, xa.z, xa.w };
            const float xbv[4] = { xb.x, xb.y, xb.z, xb.w };
#pragma unroll
            for (int k = 0; k < 4; ++k) {
                const float4* fxr =
                    reinterpret_cast<const float4*>(&FxT[4 * wi + k][0]);
                const float4 f0 = fxr[0], f1 = fxr[1], f2 = fxr[2],
                             f3 = fxr[3], f4 = fxr[4];
                const float2 f5 =
                    *reinterpret_cast<const float2*>(&FxT[4 * wi + k][20]);
                const float fv[22] = { f0.x, f0.y, f0.z, f0.w,
                                       f1.x, f1.y, f1.z, f1.w,
                                       f2.x, f2.y, f2.z, f2.w,
                                       f3.x, f3.y, f3.z, f3.w,
                                       f4.x, f4.y, f4.z, f4.w,
                                       f5.x, f5.y };
                const float va = xav[k], vb = xbv[k];
#pragma unroll
                for (int j = 0; j < 22; ++j) {
                    a0[j] += va * fv[j];
                    a1[j] += vb * fv[j];
                }
            }
        }
    }

    // ---- half 0: store a0, consume via GEMM2 (Fy rows 0..31) ----
    {
        float2* d0 = reinterpret_cast<float2*>(&t2s[c_loc][hl][0]);
#pragma unroll
        for (int p = 0; p < 11; ++p)
            d0[p] = make_float2(a0[2 * p], a0[2 * p + 1]);
        d0[11] = make_float2(0.f, 0.f);
    }
    __syncthreads();
    {
#pragma unroll 4
        for (int hp2 = 0; hp2 < 32; ++hp2) {
            const float4 fy = *reinterpret_cast<const float4*>(&FyT[hp2][i0r]);
            const float2* tp =
                reinterpret_cast<const float2*>(&t2s[c_loc][hp2][j0]);
            const float2 q0 = tp[0], q1 = tp[1], q2 = tp[2];
            const float fyv[4] = { fy.x, fy.y, fy.z, fy.w };
            const float tv[6]  = { q0.x, q0.y, q1.x, q1.y, q2.x, q2.y };
#pragma unroll
            for (int r = 0; r < 4; ++r)
#pragma unroll
                for (int s2 = 0; s2 < 6; ++s2)
                    acc2[r][s2] += fyv[r] * tv[s2];
        }
    }
    __syncthreads();

    // ---- half 1: store a1, consume via GEMM2 (Fy rows 32..63) ----
    {
        float2* d1 = reinterpret_cast<float2*>(&t2s[c_loc][hl][0]);
#pragma unroll
        for (int p = 0; p < 11; ++p)
            d1[p] = make_float2(a1[2 * p], a1[2 * p + 1]);
        d1[11] = make_float2(0.f, 0.f);
    }
    __syncthreads();
    {
#pragma unroll 4
        for (int hp2 = 0; hp2 < 32; ++hp2) {
            const float4 fy =
                *reinterpret_cast<const float4*>(&FyT[32 + hp2][i0r]);
            const float2* tp =
                reinterpret_cast<const float2*>(&t2s[c_loc][hp2][j0]);
            const float2 q0 = tp[0], q1 = tp[1], q2 = tp[2];
            const float fyv[4] = { fy.x, fy.y, fy.z, fy.w };
            const float tv[6]  = { q0.x, q0.y, q1.x, q1.y, q2.x, q2.y };
#pragma unroll
            for (int r = 0; r < 4; ++r)
#pragma unroll
                for (int s2 = 0; s2 < 6; ++s2)
                    acc2[r][s2] += fyv[r] * tv[s2];
        }
    }

    // ---- store glimpse tile: g[nt][c][i][j], 32x22 per channel ----
    const size_t gb = ((size_t)nt * 64 + (size_t)(cg * 8 + c_loc)) * 704;
#pragma unroll
    for (int r = 0; r < 4; ++r) {
#pragma unroll
        for (int s2 = 0; s2 < 6; ++s2) {
            const int j = j0 + s2;
            if (j < 22) {
                g[gb + (size_t)((i0r + r) * 22 + j)] = acc2[r][s2];
            }
        }
    }
}

// ---------------------------------------------------------------- kernel B
__global__ __launch_bounds__(256) void gather_kernel(
    const float* __restrict__ g,
    const float* __restrict__ dtp, const float* __restrict__ ldt,
    const float* __restrict__ lgt,
    float* __restrict__ out)
{
    const int tid = threadIdx.x;
    int b = blockIdx.x;
    const int cg = b & 7; b >>= 3;
    const int tq = b % 30;
    const int n  = b / 30;

    const float dtv     = tanhf(dtp[n]) * 15.f + 15.f;
    const float delta_t = expf(ldt[n]);
    const float gamma_t = 1.f / (1.f + expf(-lgt[n]));
    float mu_t = dtv + ((float)tq - 15.f) * delta_t;
    mu_t = mu_t / 29.f * 2.f - 1.f;
    const float iy  = ((mu_t + 1.f) * 30.f - 1.f) * 0.5f;
    const float iy0 = floorf(iy);
    const float w1  = iy - iy0;
    const int   i0  = (int)iy0;
    const int   i1  = i0 + 1;
    const float W0 = (i0 >= 0 && i0 < 30) ? 0.5f * gamma_t * (1.f - w1) : 0.f;
    const float W1 = (i1 >= 0 && i1 < 30) ? 0.5f * gamma_t * w1 : 0.f;
    const int t0 = min(max(i0, 0), 29);
    const int t1 = min(max(i1, 0), 29);
    const int nt0 = n * 30 + t0;
    const int nt1 = n * 30 + t1;

    const float4* g4 = reinterpret_cast<const float4*>(g);
    float4*       o4 = reinterpret_cast<float4*>(out);

    // main rows: out floats 176..879 per (n,c,tq)  <-  g floats 0..703
    for (int idx = tid; idx < 8 * 176; idx += 256) {
        const int cl = idx / 176, k = idx % 176;
        const int c  = cg * 8 + cl;
        const float4 ga = g4[((size_t)nt0 * 64 + c) * 176 + k];
        const float4 gb = g4[((size_t)nt1 * 64 + c) * 176 + k];
        float4 r;
        r.x = W0 * ga.x + W1 * gb.x;
        r.y = W0 * ga.y + W1 * gb.y;
        r.z = W0 * ga.z + W1 * gb.z;
        r.w = W0 * ga.w + W1 * gb.w;
        o4[(((size_t)n * 64 + c) * 30 + tq) * 264 + 44 + k] = r;
    }
    // pad rows: float4 0..43 (rows 0..7) and 220..263 (rows 40..47)
    for (int idx = tid; idx < 8 * 88; idx += 256) {
        const int cl = idx / 88, k = idx % 88;
        const int c  = cg * 8 + cl;
        const int off = (k < 44) ? k : (k + 176);
        o4[(((size_t)n * 64 + c) * 30 + tq) * 264 + off] =
            make_float4(0.f, 0.f, 0.f, 0.f);
    }
}

// ------------------------------------------------- fallback (round-4 fused)
__global__ __launch_bounds__(256) void gst_fallback(
    const float* __restrict__ x,
    const float* __restrict__ dx,  const float* __restrict__ dy,
    const float* __restrict__ ls2, const float* __restrict__ ld,
    const float* __restrict__ lg,
    const float* __restrict__ dtp, const float* __restrict__ ldt,
    const float* __restrict__ lgt,
    float* __restrict__ out)
{
    __shared__ float FyT[64][32];
    __shared__ float FxT[44][24];
    __shared__ float t2s[8][32][26];

    const int tid = threadIdx.x;
    int b = blockIdx.x;
    const int cg = b & 7; b >>= 3;
    const int tq = b % 30;
    const int n  = b / 30;

    const float dtv     = tanhf(dtp[n]) * 15.f + 15.f;
    const float delta_t = expf(ldt[n]);
    const float gamma_t = 1.f / (1.f + expf(-lgt[n]));
    float mu_t = dtv + ((float)tq - 15.f) * delta_t;
    mu_t = mu_t / 29.f * 2.f - 1.f;
    const float iy  = ((mu_t + 1.f) * 30.f - 1.f) * 0.5f;
    const float iy0 = floorf(iy);
    const float w1  = iy - iy0;
    const int   i0  = (int)iy0;
    const int   i1  = i0 + 1;
    const float W0 = (i0 >= 0 && i0 < 30) ? 0.5f * gamma_t * (1.f - w1) : 0.f;
    const float W1 = (i1 >= 0 && i1 < 30) ? 0.5f * gamma_t * w1 : 0.f;
    const int t0 = min(max(i0, 0), 29);
    const int t1 = min(max(i1, 0), 29);

    const int c_loc = tid >> 5;
    const int hl    = tid & 31;
    const int jt    = tid & 3;
    const int it    = (tid >> 2) & 7;
    const int j0    = 6 * jt;
    const int i0r   = 4 * it;

    const size_t ob =
        (((size_t)n * 64 + (size_t)(cg * 8)) * 30 + (size_t)tq) * 1056;
    for (int idx = tid; idx < 8 * 16 * 22; idx += 256) {
        const int c   = idx / 352;
        const int rem = idx % 352;
        const int r   = rem / 22;
        const int j   = rem % 22;
        const int ip  = (r < 8) ? r : (r + 32);
        out[ob + (size_t)c * 31680 + (size_t)(ip * 22 + j)] = 0.f;
    }

    float acc2[4][6];
#pragma unroll
    for (int r = 0; r < 4; ++r)
#pragma unroll
        for (int s2 = 0; s2 < 6; ++s2) acc2[r][s2] = 0.f;

    bool first = true;
#pragma unroll 1
    for (int s = 0; s < 2; ++s) {
        const float Ws = s ? W1 : W0;
        const int   ts = s ? t1 : t0;
        if (Ws == 0.f) continue;
        if (!first) __syncthreads();
        first = false;

        const int nt = n * 30 + ts;
        const float sigma2 = expf(ls2[nt]);
        const float inv2s2 = 0.5f / sigma2;
        const float delta  = expf(ld[nt]);
        const float gamma  = 1.f / (1.f + expf(-lg[nt]));
        const float A      = Ws * gamma;

        if (tid < 128) {
            const int i = tid >> 2, q = tid & 3;
            float pod = dy[nt] + 0.5f * (ts >= 1 ? dy[nt - 1] : 0.f)
                               + 0.5f * (ts >= 2 ? dy[nt - 2] : 0.f);
            const float mu = tanhf(pod) * 32.f + 32.f + ((float)i - 16.f) * delta;
            float e[16];
            float sum = 0.f;
#pragma unroll
            for (int k = 0; k < 16; ++k) {
                const float d = (float)(16 * q + k) - mu;
                e[k] = expf(-d * d * inv2s2);
                sum += e[k];
            }
            sum += __shfl_xor(sum, 1);
            sum += __shfl_xor(sum, 2);
            const float sc = A / fmaxf(sum, EPS_);
#pragma unroll
            for (int k = 0; k < 16; ++k)
                FyT[16 * q + k][i] = e[k] * sc;
        } else {
            const int tx = tid - 128;
            const int j = tx >> 2, q = tx & 3;
            float pod = dx[nt] + 0.5f * (ts >= 1 ? dx[nt - 1] : 0.f)
                               + 0.5f * (ts >= 2 ? dx[nt - 2] : 0.f);
            const float mu = tanhf(pod) * 22.f + 22.f + ((float)j - 11.f) * delta;
            float e[11];
            float sum = 0.f;
#pragma unroll
            for (int m = 0; m < 11; ++m) {
                const float d = (float)(11 * q + m) - mu;
                e[m] = expf(-d * d * inv2s2);
                sum += e[m];
            }
            sum += __shfl_xor(sum, 1);
            sum += __shfl_xor(sum, 2);
            const float sc = 1.f / fmaxf(sum, EPS_);
            if (j < 22) {
#pragma unroll
                for (int m = 0; m < 11; ++m)
                    FxT[11 * q + m][j] = e[m] * sc;
            }
        }
        if (tid < 88) {
            FxT[tid >> 1][22 + (tid & 1)] = 0.f;
        }
        __syncthreads();

        float a0[22], a1[22];
#pragma unroll
        for (int j = 0; j < 22; ++j) { a0[j] = 0.f; a1[j] = 0.f; }
        {
            const size_t xoff =
                ((((size_t)n * 64 + (size_t)(cg * 8 + c_loc)) * 30
                  + (size_t)ts) * 64 + (size_t)hl) * 44;
            const float4* xr0 = reinterpret_cast<const float4*>(x + xoff);
            const float4* xr1 = reinterpret_cast<const float4*>(x + xoff + 32 * 44);

#pragma unroll 2
            for (int wi = 0; wi < 11; ++wi) {
                const float4 xa = xr0[wi];
                const float4 xb = xr1[wi];
                const float xav[4] = { xa.x, xa.y, xa.z, xa.w };
                const float xbv[4] = { xb.x, xb.y, xb.z, xb.w };
#pragma unroll
                for (int k = 0; k < 4; ++k) {
                    const float4* fxr =
                        reinterpret_cast<const float4*>(&FxT[4 * wi + k][0]);
                    const float4 f0 = fxr[0], f1 = fxr[1], f2 = fxr[2],
                                 f3 = fxr[3], f4 = fxr[4];
                    const float2 f5 =
                        *reinterpret_cast<const float2*>(&FxT[4 * wi + k][20]);
                    const float fv[22] = { f0.x, f0.y, f0.z, f0.w,
                                           f1.x, f1.y, f1.z, f1.w,
                                           f2.x, f2.y, f2.z, f2.w,
                                           f3.x, f3.y, f3.z, f3.w,
                                           f4.x, f4.y, f4.z, f4.w,
                                           f5.x, f5.y };
                    const float va = xav[k], vb = xbv[k];
#pragma unroll
                    for (int j = 0; j < 22; ++j) {
                        a0[j] += va * fv[j];
                        a1[j] += vb * fv[j];
                    }
                }
            }
        }

        {
            float2* d0 = reinterpret_cast<float2*>(&t2s[c_loc][hl][0]);
#pragma unroll
            for (int p = 0; p < 11; ++p)
                d0[p] = make_float2(a0[2 * p], a0[2 * p + 1]);
            d0[11] = make_float2(0.f, 0.f);
        }
        __syncthreads();
        {
#pragma unroll 4
            for (int hp2 = 0; hp2 < 32; ++hp2) {
                const float4 fy =
                    *reinterpret_cast<const float4*>(&FyT[hp2][i0r]);
                const float2* tp =
                    reinterpret_cast<const float2*>(&t2s[c_loc][hp2][j0]);
                const float2 q0 = tp[0], q1 = tp[1], q2 = tp[2];
                const float fyv[4] = { fy.x, fy.y, fy.z, fy.w };
                const float tv[6]  = { q0.x, q0.y, q1.x, q1.y, q2.x, q2.y };
#pragma unroll
                for (int r = 0; r < 4; ++r)
#pragma unroll
                    for (int s2 = 0; s2 < 6; ++s2)
                        acc2[r][s2] += fyv[r] * tv[s2];
            }
        }
        __syncthreads();

        {
            float2* d1 = reinterpret_cast<float2*>(&t2s[c_loc][hl][0]);
#pragma unroll
            for (int p = 0; p < 11; ++p)
                d1[p] = make_float2(a1[2 * p], a1[2 * p + 1]);
            d1[11] = make_float2(0.f, 0.f);
        }
        __syncthreads();
        {
#pragma unroll 4
            for (int hp2 = 0; hp2 < 32; ++hp2) {
                const float4 fy =
                    *reinterpret_cast<const float4*>(&FyT[32 + hp2][i0r]);
                const float2* tp =
                    reinterpret_cast<const float2*>(&t2s[c_loc][hp2][j0]);
                const float2 q0 = tp[0], q1 = tp[1], q2 = tp[2];
                const float fyv[4] = { fy.x, fy.y, fy.z, fy.w };
                const float tv[6]  = { q0.x, q0.y, q1.x, q1.y, q2.x, q2.y };
#pragma unroll
                for (int r = 0; r < 4; ++r)
#pragma unroll
                    for (int s2 = 0; s2 < 6; ++s2)
                        acc2[r][s2] += fyv[r] * tv[s2];
            }
        }
    }

#pragma unroll
    for (int r = 0; r < 4; ++r) {
#pragma unroll
        for (int s2 = 0; s2 < 6; ++s2) {
            const int j = j0 + s2;
            if (j < 22) {
                out[ob + (size_t)c_loc * 31680
                       + (size_t)((8 + i0r + r) * 22 + j)] = acc2[r][s2];
            }
        }
    }
}

extern "C" void kernel_launch(void* const* d_in, const int* in_sizes, int n_in,
                              void* d_out, int out_size, void* d_ws, size_t ws_size,
                              hipStream_t stream) {
    const float* x   = (const float*)d_in[0];
    const float* dx  = (const float*)d_in[1];
    const float* dy  = (const float*)d_in[2];
    const float* ls2 = (const float*)d_in[3];
    const float* ld  = (const float*)d_in[4];
    const float* lg  = (const float*)d_in[5];
    const float* dtp = (const float*)d_in[6];
    const float* ldt = (const float*)d_in[7];
    const float* lgt = (const float*)d_in[8];
    float* out = (float*)d_out;

    dim3 grid(16 * 30 * 8), block(256);

    if (d_ws != nullptr && ws_size >= GLIMPSE_BYTES) {
        float* g = (float*)d_ws;
        hipLaunchKernelGGL(glimpse_kernel, grid, block, 0, stream,
                           x, dx, dy, ls2, ld, lg, g);
        hipLaunchKernelGGL(gather_kernel, grid, block, 0, stream,
                           g, dtp, ldt, lgt, out);
    } else {
        hipLaunchKernelGGL(gst_fallback, grid, block, 0, stream,
                           x, dx, dy, ls2, ld, lg, dtp, ldt, lgt, out);
    }
}

// Round 8
// 695.426 us; speedup vs baseline: 1.1262x; 1.1247x over previous
//
#include <hip/hip_runtime.h>
#include <math.h>

// GaussianSampleST split into 2 kernels (fp32):
//  A) glimpse2_kernel: per-source glimpse g[n][t][c][32][22] (gamma folded),
//     each source computed ONCE.  Each block handles TWO sources
//     (t = 2*tq2, 2*tq2+1) inside a `#pragma unroll 1` loop — the SAME loop
//     shape as the round-4 fused kernel.  Evidence (5 rounds): this body
//     inside such a loop compiles to 124 VGPR spill-free; straight-line it
//     compiles to 60 VGPR + scratch (L2 thrash: FETCH 1.2GB, 376us).
//     The `t >= Tdyn` guard (Tdyn=30 runtime arg) keeps the block-uniform
//     branch shape without ever taken.
//  B) gather_kernel: out[n][c][tq] = W0*g[t0] + W1*g[t1] + zero-pad,
//     pure float4 streaming (memory-bound).
// Fallback: if ws_size < 86.5MB, launch the fused round-4 kernel.

#define EPS_ 1e-8f
#define GLIMPSE_BYTES (16ull * 30ull * 64ull * 704ull * 4ull)  // 86,507,520

// ---------------------------------------------------------------- kernel A
__global__ __launch_bounds__(256) void glimpse2_kernel(
    const float* __restrict__ x,
    const float* __restrict__ dx,  const float* __restrict__ dy,
    const float* __restrict__ ls2, const float* __restrict__ ld,
    const float* __restrict__ lg,
    float* __restrict__ g,
    int Tdyn)
{
    __shared__ float FyT[64][32];     // [h][i]  (Fy, pre-scaled by gamma)
    __shared__ float FxT[44][24];     // [w][j]  (cols 22/23 zeroed)
    __shared__ float t2s[8][32][26];  // [c][h-in-half][j], stride 26

    const int tid = threadIdx.x;
    int b = blockIdx.x;
    const int cg  = b & 7; b >>= 3;
    const int tq2 = b % 15;
    const int n   = b / 15;

    const int c_loc = tid >> 5;        // 0..7
    const int hl    = tid & 31;        // GEMM1: rows h=hl and h=32+hl
    const int jt    = tid & 3;         // GEMM2: j-tile base 6*jt
    const int it    = (tid >> 2) & 7;  // GEMM2: i-tile base 4*it
    const int j0    = 6 * jt;
    const int i0r   = 4 * it;

    bool first = true;
#pragma unroll 1
    for (int s = 0; s < 2; ++s) {
        const int t = 2 * tq2 + s;
        if (t >= Tdyn) continue;          // block-uniform, never taken (Tdyn=30)
        if (!first) __syncthreads();      // protect LDS reuse from previous source
        first = false;

        // ---- per-source attention params into LDS (all 256 lanes) ----
        const int nt = n * 30 + t;
        const float sigma2 = expf(ls2[nt]);
        const float inv2s2 = 0.5f / sigma2;
        const float delta  = expf(ld[nt]);
        const float gamma  = 1.f / (1.f + expf(-lg[nt]));

        if (tid < 128) {
            // Fy: col i = tid>>2 (0..31), quarter q = tid&3 covers h = 16q..16q+15
            const int i = tid >> 2, q = tid & 3;
            float pod = dy[nt] + 0.5f * (t >= 1 ? dy[nt - 1] : 0.f)
                               + 0.5f * (t >= 2 ? dy[nt - 2] : 0.f);
            const float mu = tanhf(pod) * 32.f + 32.f + ((float)i - 16.f) * delta;
            float e[16];
            float sum = 0.f;
#pragma unroll
            for (int k = 0; k < 16; ++k) {
                const float d = (float)(16 * q + k) - mu;
                e[k] = expf(-d * d * inv2s2);
                sum += e[k];
            }
            sum += __shfl_xor(sum, 1);
            sum += __shfl_xor(sum, 2);
            const float sc = gamma / fmaxf(sum, EPS_);
#pragma unroll
            for (int k = 0; k < 16; ++k)
                FyT[16 * q + k][i] = e[k] * sc;
        } else {
            // Fx: col j = (tid-128)>>2, quarter q covers w = 11q..11q+10
            const int tx = tid - 128;
            const int j = tx >> 2, q = tx & 3;
            float pod = dx[nt] + 0.5f * (t >= 1 ? dx[nt - 1] : 0.f)
                               + 0.5f * (t >= 2 ? dx[nt - 2] : 0.f);
            const float mu = tanhf(pod) * 22.f + 22.f + ((float)j - 11.f) * delta;
            float e[11];
            float sum = 0.f;
#pragma unroll
            for (int m = 0; m < 11; ++m) {
                const float d = (float)(11 * q + m) - mu;
                e[m] = expf(-d * d * inv2s2);
                sum += e[m];
            }
            sum += __shfl_xor(sum, 1);
            sum += __shfl_xor(sum, 2);
            const float sc = 1.f / fmaxf(sum, EPS_);
            if (j < 22) {
#pragma unroll
                for (int m = 0; m < 11; ++m)
                    FxT[11 * q + m][j] = e[m] * sc;
            }
        }
        if (tid < 88) {
            FxT[tid >> 1][22 + (tid & 1)] = 0.f;   // pad cols read-safe
        }
        __syncthreads();

        float acc2[4][6];
#pragma unroll
        for (int r = 0; r < 4; ++r)
#pragma unroll
            for (int s2 = 0; s2 < 6; ++s2) acc2[r][s2] = 0.f;

        // ---- GEMM1 (all 256 threads): rows h=hl (->a0), h=32+hl (->a1) ----
        float a0[22], a1[22];
#pragma unroll
        for (int j = 0; j < 22; ++j) { a0[j] = 0.f; a1[j] = 0.f; }
        {
            const size_t xoff =
                ((((size_t)n * 64 + (size_t)(cg * 8 + c_loc)) * 30
                  + (size_t)t) * 64 + (size_t)hl) * 44;
            const float4* xr0 = reinterpret_cast<const float4*>(x + xoff);
            const float4* xr1 = reinterpret_cast<const float4*>(x + xoff + 32 * 44);

#pragma unroll 2
            for (int wi = 0; wi < 11; ++wi) {
                const float4 xa = xr0[wi];
                const float4 xb = xr1[wi];
                const float xav[4] = { xa.x, xa.y, xa.z, xa.w };
                const float xbv[4] = { xb.x, xb.y, xb.z, xb.w };
#pragma unroll
                for (int k = 0; k < 4; ++k) {
                    const float4* fxr =
                        reinterpret_cast<const float4*>(&FxT[4 * wi + k][0]);
                    const float4 f0 = fxr[0], f1 = fxr[1], f2 = fxr[2],
                                 f3 = fxr[3], f4 = fxr[4];
                    const float2 f5 =
                        *reinterpret_cast<const float2*>(&FxT[4 * wi + k][20]);
                    const float fv[22] = { f0.x, f0.y, f0.z, f0.w,
                                           f1.x, f1.y, f1.z, f1.w,
                                           f2.x, f2.y, f2.z, f2.w,
                                           f3.x, f3.y, f3.z, f3.w,
                                           f4.x, f4.y, f4.z, f4.w,
                                           f5.x, f5.y };
                    const float va = xav[k], vb = xbv[k];
#pragma unroll
                    for (int j = 0; j < 22; ++j) {
                        a0[j] += va * fv[j];
                        a1[j] += vb * fv[j];
                    }
                }
            }
        }

        // ---- half 0: store a0, consume via GEMM2 (Fy rows 0..31) ----
        {
            float2* d0 = reinterpret_cast<float2*>(&t2s[c_loc][hl][0]);
#pragma unroll
            for (int p = 0; p < 11; ++p)
                d0[p] = make_float2(a0[2 * p], a0[2 * p + 1]);
            d0[11] = make_float2(0.f, 0.f);
        }
        __syncthreads();
        {
#pragma unroll 4
            for (int hp2 = 0; hp2 < 32; ++hp2) {
                const float4 fy =
                    *reinterpret_cast<const float4*>(&FyT[hp2][i0r]);
                const float2* tp =
                    reinterpret_cast<const float2*>(&t2s[c_loc][hp2][j0]);
                const float2 q0 = tp[0], q1 = tp[1], q2 = tp[2];
                const float fyv[4] = { fy.x, fy.y, fy.z, fy.w };
                const float tv[6]  = { q0.x, q0.y, q1.x, q1.y, q2.x, q2.y };
#pragma unroll
                for (int r = 0; r < 4; ++r)
#pragma unroll
                    for (int s2 = 0; s2 < 6; ++s2)
                        acc2[r][s2] += fyv[r] * tv[s2];
            }
        }
        __syncthreads();

        // ---- half 1: store a1, consume via GEMM2 (Fy rows 32..63) ----
        {
            float2* d1 = reinterpret_cast<float2*>(&t2s[c_loc][hl][0]);
#pragma unroll
            for (int p = 0; p < 11; ++p)
                d1[p] = make_float2(a1[2 * p], a1[2 * p + 1]);
            d1[11] = make_float2(0.f, 0.f);
        }
        __syncthreads();
        {
#pragma unroll 4
            for (int hp2 = 0; hp2 < 32; ++hp2) {
                const float4 fy =
                    *reinterpret_cast<const float4*>(&FyT[32 + hp2][i0r]);
                const float2* tp =
                    reinterpret_cast<const float2*>(&t2s[c_loc][hp2][j0]);
                const float2 q0 = tp[0], q1 = tp[1], q2 = tp[2];
                const float fyv[4] = { fy.x, fy.y, fy.z, fy.w };
                const float tv[6]  = { q0.x, q0.y, q1.x, q1.y, q2.x, q2.y };
#pragma unroll
                for (int r = 0; r < 4; ++r)
#pragma unroll
                    for (int s2 = 0; s2 < 6; ++s2)
                        acc2[r][s2] += fyv[r] * tv[s2];
            }
        }

        // ---- store glimpse tile for this source: g[nt][c][i][j] ----
        const size_t gb = ((size_t)nt * 64 + (size_t)(cg * 8 + c_loc)) * 704;
#pragma unroll
        for (int r = 0; r < 4; ++r) {
#pragma unroll
            for (int s2 = 0; s2 < 6; ++s2) {
                const int j = j0 + s2;
                if (j < 22) {
                    g[gb + (size_t)((i0r + r) * 22 + j)] = acc2[r][s2];
                }
            }
        }
    }
}

// ---------------------------------------------------------------- kernel B
__global__ __launch_bounds__(256) void gather_kernel(
    const float* __restrict__ g,
    const float* __restrict__ dtp, const float* __restrict__ ldt,
    const float* __restrict__ lgt,
    float* __restrict__ out)
{
    const int tid = threadIdx.x;
    int b = blockIdx.x;
    const int cg = b & 7; b >>= 3;
    const int tq = b % 30;
    const int n  = b / 30;

    const float dtv     = tanhf(dtp[n]) * 15.f + 15.f;
    const float delta_t = expf(ldt[n]);
    const float gamma_t = 1.f / (1.f + expf(-lgt[n]));
    float mu_t = dtv + ((float)tq - 15.f) * delta_t;
    mu_t = mu_t / 29.f * 2.f - 1.f;
    const float iy  = ((mu_t + 1.f) * 30.f - 1.f) * 0.5f;
    const float iy0 = floorf(iy);
    const float w1  = iy - iy0;
    const int   i0  = (int)iy0;
    const int   i1  = i0 + 1;
    const float W0 = (i0 >= 0 && i0 < 30) ? 0.5f * gamma_t * (1.f - w1) : 0.f;
    const float W1 = (i1 >= 0 && i1 < 30) ? 0.5f * gamma_t * w1 : 0.f;
    const int t0 = min(max(i0, 0), 29);
    const int t1 = min(max(i1, 0), 29);
    const int nt0 = n * 30 + t0;
    const int nt1 = n * 30 + t1;

    const float4* g4 = reinterpret_cast<const float4*>(g);
    float4*       o4 = reinterpret_cast<float4*>(out);

    // main rows: out floats 176..879 per (n,c,tq)  <-  g floats 0..703
    for (int idx = tid; idx < 8 * 176; idx += 256) {
        const int cl = idx / 176, k = idx % 176;
        const int c  = cg * 8 + cl;
        const float4 ga = g4[((size_t)nt0 * 64 + c) * 176 + k];
        const float4 gb = g4[((size_t)nt1 * 64 + c) * 176 + k];
        float4 r;
        r.x = W0 * ga.x + W1 * gb.x;
        r.y = W0 * ga.y + W1 * gb.y;
        r.z = W0 * ga.z + W1 * gb.z;
        r.w = W0 * ga.w + W1 * gb.w;
        o4[(((size_t)n * 64 + c) * 30 + tq) * 264 + 44 + k] = r;
    }
    // pad rows: float4 0..43 (rows 0..7) and 220..263 (rows 40..47)
    for (int idx = tid; idx < 8 * 88; idx += 256) {
        const int cl = idx / 88, k = idx % 88;
        const int c  = cg * 8 + cl;
        const int off = (k < 44) ? k : (k + 176);
        o4[(((size_t)n * 64 + c) * 30 + tq) * 264 + off] =
            make_float4(0.f, 0.f, 0.f, 0.f);
    }
}

// ------------------------------------------------- fallback (round-4 fused)
__global__ __launch_bounds__(256) void gst_fallback(
    const float* __restrict__ x,
    const float* __restrict__ dx,  const float* __restrict__ dy,
    const float* __restrict__ ls2, const float* __restrict__ ld,
    const float* __restrict__ lg,
    const float* __restrict__ dtp, const float* __restrict__ ldt,
    const float* __restrict__ lgt,
    float* __restrict__ out)
{
    __shared__ float FyT[64][32];
    __shared__ float FxT[44][24];
    __shared__ float t2s[8][32][26];

    const int tid = threadIdx.x;
    int b = blockIdx.x;
    const int cg = b & 7; b >>= 3;
    const int tq = b % 30;
    const int n  = b / 30;

    const float dtv     = tanhf(dtp[n]) * 15.f + 15.f;
    const float delta_t = expf(ldt[n]);
    const float gamma_t = 1.f / (1.f + expf(-lgt[n]));
    float mu_t = dtv + ((float)tq - 15.f) * delta_t;
    mu_t = mu_t / 29.f * 2.f - 1.f;
    const float iy  = ((mu_t + 1.f) * 30.f - 1.f) * 0.5f;
    const float iy0 = floorf(iy);
    const float w1  = iy - iy0;
    const int   i0  = (int)iy0;
    const int   i1  = i0 + 1;
    const float W0 = (i0 >= 0 && i0 < 30) ? 0.5f * gamma_t * (1.f - w1) : 0.f;
    const float W1 = (i1 >= 0 && i1 < 30) ? 0.5f * gamma_t * w1 : 0.f;
    const int t0 = min(max(i0, 0), 29);
    const int t1 = min(max(i1, 0), 29);

    const int c_loc = tid >> 5;
    const int hl    = tid & 31;
    const int jt    = tid & 3;
    const int it    = (tid >> 2) & 7;
    const int j0    = 6 * jt;
    const int i0r   = 4 * it;

    const size_t ob =
        (((size_t)n * 64 + (size_t)(cg * 8)) * 30 + (size_t)tq) * 1056;
    for (int idx = tid; idx < 8 * 16 * 22; idx += 256) {
        const int c   = idx / 352;
        const int rem = idx % 352;
        const int r   = rem / 22;
        const int j   = rem % 22;
        const int ip  = (r < 8) ? r : (r + 32);
        out[ob + (size_t)c * 31680 + (size_t)(ip * 22 + j)] = 0.f;
    }

    float acc2[4][6];
#pragma unroll
    for (int r = 0; r < 4; ++r)
#pragma unroll
        for (int s2 = 0; s2 < 6; ++s2) acc2[r][s2] = 0.f;

    bool first = true;
#pragma unroll 1
    for (int s = 0; s < 2; ++s) {
        const float Ws = s ? W1 : W0;
        const int   ts = s ? t1 : t0;
        if (Ws == 0.f) continue;
        if (!first) __syncthreads();
        first = false;

        const int nt = n * 30 + ts;
        const float sigma2 = expf(ls2[nt]);
        const float inv2s2 = 0.5f / sigma2;
        const float delta  = expf(ld[nt]);
        const float gamma  = 1.f / (1.f + expf(-lg[nt]));
        const float A      = Ws * gamma;

        if (tid < 128) {
            const int i = tid >> 2, q = tid & 3;
            float pod = dy[nt] + 0.5f * (ts >= 1 ? dy[nt - 1] : 0.f)
                               + 0.5f * (ts >= 2 ? dy[nt - 2] : 0.f);
            const float mu = tanhf(pod) * 32.f + 32.f + ((float)i - 16.f) * delta;
            float e[16];
            float sum = 0.f;
#pragma unroll
            for (int k = 0; k < 16; ++k) {
                const float d = (float)(16 * q + k) - mu;
                e[k] = expf(-d * d * inv2s2);
                sum += e[k];
            }
            sum += __shfl_xor(sum, 1);
            sum += __shfl_xor(sum, 2);
            const float sc = A / fmaxf(sum, EPS_);
#pragma unroll
            for (int k = 0; k < 16; ++k)
                FyT[16 * q + k][i] = e[k] * sc;
        } else {
            const int tx = tid - 128;
            const int j = tx >> 2, q = tx & 3;
            float pod = dx[nt] + 0.5f * (ts >= 1 ? dx[nt - 1] : 0.f)
                               + 0.5f * (ts >= 2 ? dx[nt - 2] : 0.f);
            const float mu = tanhf(pod) * 22.f + 22.f + ((float)j - 11.f) * delta;
            float e[11];
            float sum = 0.f;
#pragma unroll
            for (int m = 0; m < 11; ++m) {
                const float d = (float)(11 * q + m) - mu;
                e[m] = expf(-d * d * inv2s2);
                sum += e[m];
            }
            sum += __shfl_xor(sum, 1);
            sum += __shfl_xor(sum, 2);
            const float sc = 1.f / fmaxf(sum, EPS_);
            if (j < 22) {
#pragma unroll
                for (int m = 0; m < 11; ++m)
                    FxT[11 * q + m][j] = e[m] * sc;
            }
        }
        if (tid < 88) {
            FxT[tid >> 1][22 + (tid & 1)] = 0.f;
        }
        __syncthreads();

        float a0[22], a1[22];
#pragma unroll
        for (int j = 0; j < 22; ++j) { a0[j] = 0.f; a1[j] = 0.f; }
        {
            const size_t xoff =
                ((((size_t)n * 64 + (size_t)(cg * 8 + c_loc)) * 30
                  + (size_t)ts) * 64 + (size_t)hl) * 44;
            const float4* xr0 = reinterpret_cast<const float4*>(x + xoff);
            const float4* xr1 = reinterpret_cast<const float4*>(x + xoff + 32 * 44);

#pragma unroll 2
            for (int wi = 0; wi < 11; ++wi) {
                const float4 xa = xr0[wi];
                const float4 xb = xr1[wi];
                const float xav[4] = { xa.x, xa.y, xa.z, xa.w };
                const float xbv[4] = { xb.x, xb.y, xb.z, xb.w };
#pragma unroll
                for (int k = 0; k < 4; ++k) {
                    const float4* fxr =
                        reinterpret_cast<const float4*>(&FxT[4 * wi + k][0]);
                    const float4 f0 = fxr[0], f1 = fxr[1], f2 = fxr[2],
                                 f3 = fxr[3], f4 = fxr[4];
                    const float2 f5 =
                        *reinterpret_cast<const float2*>(&FxT[4 * wi + k][20]);
                    const float fv[22] = { f0.x, f0.y, f0.z, f0.w,
                                           f1.x, f1.y, f1.z, f1.w,
                                           f2.x, f2.y, f2.z, f2.w,
                                           f3.x, f3.y, f3.z, f3.w,
                                           f4.x, f4.y, f4.z, f4.w,
                                           f5.x, f5.y };
                    const float va = xav[k], vb = xbv[k];
#pragma unroll
                    for (int j = 0; j < 22; ++j) {
                        a0[j] += va * fv[j];
                        a1[j] += vb * fv[j];
                    }
                }
            }
        }

        {
            float2* d0 = reinterpret_cast<float2*>(&t2s[c_loc][hl][0]);
#pragma unroll
            for (int p = 0; p < 11; ++p)
                d0[p] = make_float2(a0[2 * p], a0[2 * p + 1]);
            d0[11] = make_float2(0.f, 0.f);
        }
        __syncthreads();
        {
#pragma unroll 4
            for (int hp2 = 0; hp2 < 32; ++hp2) {
                const float4 fy =
                    *reinterpret_cast<const float4*>(&FyT[hp2][i0r]);
                const float2* tp =
                    reinterpret_cast<const float2*>(&t2s[c_loc][hp2][j0]);
                const float2 q0 = tp[0], q1 = tp[1], q2 = tp[2];
                const float fyv[4] = { fy.x, fy.y, fy.z, fy.w };
                const float tv[6]  = { q0.x, q0.y, q1.x, q1.y, q2.x, q2.y };
#pragma unroll
                for (int r = 0; r < 4; ++r)
#pragma unroll
                    for (int s2 = 0; s2 < 6; ++s2)
                        acc2[r][s2] += fyv[r] * tv[s2];
            }
        }
        __syncthreads();

        {
            float2* d1 = reinterpret_cast<float2*>(&t2s[c_loc][hl][0]);
#pragma unroll
            for (int p = 0; p < 11; ++p)
                d1[p] = make_float2(a1[2 * p], a1[2 * p + 1]);
            d1[11] = make_float2(0.f, 0.f);
        }
        __syncthreads();
        {
#pragma unroll 4
            for (int hp2 = 0; hp2 < 32; ++hp2) {
                const float4 fy =
                    *reinterpret_cast<const float4*>(&FyT[32 + hp2][i0r]);
                const float2* tp =
                    reinterpret_cast<const float2*>(&t2s[c_loc][hp2][j0]);
                const float2 q0 = tp[0], q1 = tp[1], q2 = tp[2];
                const float fyv[4] = { fy.x, fy.y, fy.z, fy.w };
                const float tv[6]  = { q0.x, q0.y, q1.x, q1.y, q2.x, q2.y };
#pragma unroll
                for (int r = 0; r < 4; ++r)
#pragma unroll
                    for (int s2 = 0; s2 < 6; ++s2)
                        acc2[r][s2] += fyv[r] * tv[s2];
            }
        }
    }

#pragma unroll
    for (int r = 0; r < 4; ++r) {
#pragma unroll
        for (int s2 = 0; s2 < 6; ++s2) {
            const int j = j0 + s2;
            if (j < 22) {
                out[ob + (size_t)c_loc * 31680
                       + (size_t)((8 + i0r + r) * 22 + j)] = acc2[r][s2];
            }
        }
    }
}

extern "C" void kernel_launch(void* const* d_in, const int* in_sizes, int n_in,
                              void* d_out, int out_size, void* d_ws, size_t ws_size,
                              hipStream_t stream) {
    const float* x   = (const float*)d_in[0];
    const float* dx  = (const float*)d_in[1];
    const float* dy  = (const float*)d_in[2];
    const float* ls2 = (const float*)d_in[3];
    const float* ld  = (const float*)d_in[4];
    const float* lg  = (const float*)d_in[5];
    const float* dtp = (const float*)d_in[6];
    const float* ldt = (const float*)d_in[7];
    const float* lgt = (const float*)d_in[8];
    float* out = (float*)d_out;

    dim3 block(256);

    if (d_ws != nullptr && ws_size >= GLIMPSE_BYTES) {
        float* g = (float*)d_ws;
        dim3 grid_a(16 * 15 * 8);   // 2 sources per block
        dim3 grid_b(16 * 30 * 8);
        hipLaunchKernelGGL(glimpse2_kernel, grid_a, block, 0, stream,
                           x, dx, dy, ls2, ld, lg, g, 30);
        hipLaunchKernelGGL(gather_kernel, grid_b, block, 0, stream,
                           g, dtp, ldt, lgt, out);
    } else {
        dim3 grid(16 * 30 * 8);
        hipLaunchKernelGGL(gst_fallback, grid, block, 0, stream,
                           x, dx, dy, ls2, ld, lg, dtp, ldt, lgt, out);
    }
}